// Round 1
// baseline (117.244 us; speedup 1.0000x reference)
//
#include <hip/hip_runtime.h>
#include <math.h>

typedef __bf16 bf16;
typedef __bf16 bf16x8 __attribute__((ext_vector_type(8)));
typedef float f32x4 __attribute__((ext_vector_type(4)));

#define MFMA16(a,b,c) __builtin_amdgcn_mfma_f32_16x16x32_bf16((a),(b),(c),0,0,0)

static constexpr int HS  = 64;    // head size
static constexpr int SEQ = 2048;  // sequence length
static constexpr int NE  = 1024;  // n_embed
static constexpr int NB  = 8;     // batch

// Load 16 f32 (64B) -> convert -> store 16 bf16 (32B) to LDS.
__device__ __forceinline__ void cvt16(const float* __restrict__ s, bf16* __restrict__ d) {
  float4 a0 = *(const float4*)(s + 0);
  float4 a1 = *(const float4*)(s + 4);
  float4 a2 = *(const float4*)(s + 8);
  float4 a3 = *(const float4*)(s + 12);
  bf16 t[16];
  t[0]=(bf16)a0.x;  t[1]=(bf16)a0.y;  t[2]=(bf16)a0.z;  t[3]=(bf16)a0.w;
  t[4]=(bf16)a1.x;  t[5]=(bf16)a1.y;  t[6]=(bf16)a1.z;  t[7]=(bf16)a1.w;
  t[8]=(bf16)a2.x;  t[9]=(bf16)a2.y;  t[10]=(bf16)a2.z; t[11]=(bf16)a2.w;
  t[12]=(bf16)a3.x; t[13]=(bf16)a3.y; t[14]=(bf16)a3.z; t[15]=(bf16)a3.w;
  *(bf16x8*)(d + 0) = *(const bf16x8*)(t + 0);
  *(bf16x8*)(d + 8) = *(const bf16x8*)(t + 8);
}

// Projection GEMM: out[row][h] = X[row][:] . W[h][:]  (bf16 MFMA, f32 inputs)
// KV=0: out=qb (scaled by 0.125). KV=1: Wa->kb row-major, Wb->vtb transposed [B][64][SEQ].
template<int KV>
__global__ __launch_bounds__(256) void proj_kernel(
    const float* __restrict__ X, const float* __restrict__ Wa,
    const float* __restrict__ Wb, bf16* __restrict__ outA,
    bf16* __restrict__ outVT)
{
  __shared__ __align__(16) bf16 Xc[64][72];   // +8 pad: balanced bank access
  __shared__ __align__(16) bf16 WcA[64][72];
  __shared__ __align__(16) bf16 WcB[64][72];

  const int tid  = threadIdx.x;
  const int lane = tid & 63;
  const int w    = tid >> 6;        // wave 0..3 -> rows 16w..16w+15
  const int m    = lane & 15;
  const int g    = lane >> 4;
  const int rowBase = blockIdx.x * 64;
  const int srow = tid >> 2;        // staging: row 0..63
  const int sseg = (tid & 3) * 16;  // staging: 16-element segment

  const f32x4 vzero = {0.f, 0.f, 0.f, 0.f};
  f32x4 accA[4] = {vzero, vzero, vzero, vzero};
  f32x4 accB[4] = {vzero, vzero, vzero, vzero};

  for (int k0 = 0; k0 < NE; k0 += 64) {
    __syncthreads();
    cvt16(X  + (size_t)(rowBase + srow) * NE + k0 + sseg, &Xc[srow][sseg]);
    cvt16(Wa + (size_t)srow * NE + k0 + sseg, &WcA[srow][sseg]);
    if (KV) cvt16(Wb + (size_t)srow * NE + k0 + sseg, &WcB[srow][sseg]);
    __syncthreads();
#pragma unroll
    for (int kk = 0; kk < 2; ++kk) {
      bf16x8 a = *(const bf16x8*)&Xc[16*w + m][kk*32 + g*8];
#pragma unroll
      for (int n = 0; n < 4; ++n) {
        bf16x8 b0 = *(const bf16x8*)&WcA[16*n + m][kk*32 + g*8];
        accA[n] = MFMA16(a, b0, accA[n]);
        if (KV) {
          bf16x8 b1 = *(const bf16x8*)&WcB[16*n + m][kk*32 + g*8];
          accB[n] = MFMA16(a, b1, accB[n]);
        }
      }
    }
  }

  // C/D layout: col = lane&15 (=m), row = 4*(lane>>4)+i (=4g+i)   [m89-verified]
#pragma unroll
  for (int n = 0; n < 4; ++n) {
#pragma unroll
    for (int i = 0; i < 4; ++i) {
      int row = rowBase + 16*w + 4*g + i;
      int h   = 16*n + m;
      float va = accA[n][i];
      if (!KV) va *= 0.125f;                 // bake 1/sqrt(64) into q
      outA[(size_t)row * HS + h] = (bf16)va;
      if (KV) {
        int bb = row >> 11;                  // row / 2048
        int ss = row & 2047;
        outVT[((size_t)bb * HS + h) * SEQ + ss] = (bf16)accB[n][i];
      }
    }
  }
}

// Flash attention: one block = 64 q-rows of one batch; 4 waves x 16 rows.
__global__ __launch_bounds__(256) void attn_kernel(
    const bf16* __restrict__ qb, const bf16* __restrict__ kb,
    const bf16* __restrict__ vtb, float* __restrict__ out)
{
  __shared__ __align__(16) bf16 Ks[64][72];       // K tile   [kv][d]
  __shared__ __align__(16) bf16 VTs[64][72];      // V^T tile [d][kv]
  __shared__ __align__(16) bf16 Ps[4][16][72];    // per-wave P [qrow][kv]

  const int tid  = threadIdx.x;
  const int lane = tid & 63;
  const int w    = tid >> 6;
  const int m    = lane & 15;
  const int g    = lane >> 4;
  const int qt   = blockIdx.x;   // q tile 0..31
  const int b    = blockIdx.y;   // batch
  const int srow = tid >> 2;
  const int sseg = (tid & 3) * 16;

  // Q fragments in registers: A-layout row = m, k = kk*32 + g*8 + j
  const int qrow = qt * 64 + 16 * w + m;
  bf16x8 qf[2];
#pragma unroll
  for (int kk = 0; kk < 2; ++kk)
    qf[kk] = *(const bf16x8*)(qb + ((size_t)b * SEQ + qrow) * HS + kk*32 + g*8);

  const f32x4 vzero = {0.f, 0.f, 0.f, 0.f};
  f32x4 o_acc[4] = {vzero, vzero, vzero, vzero};
  float mrun[4], lrun[4];
#pragma unroll
  for (int i = 0; i < 4; ++i) { mrun[i] = -INFINITY; lrun[i] = 0.f; }

  for (int j = 0; j <= qt; ++j) {
    __syncthreads();  // protect LDS reuse from previous iteration
    {
      const bf16* ks = kb + ((size_t)b * SEQ + j*64 + srow) * HS + sseg;
      *(bf16x8*)&Ks[srow][sseg]     = *(const bf16x8*)(ks);
      *(bf16x8*)&Ks[srow][sseg + 8] = *(const bf16x8*)(ks + 8);
      const bf16* vs = vtb + ((size_t)b * HS + srow) * SEQ + j*64 + sseg;
      *(bf16x8*)&VTs[srow][sseg]     = *(const bf16x8*)(vs);
      *(bf16x8*)&VTs[srow][sseg + 8] = *(const bf16x8*)(vs + 8);
    }
    __syncthreads();

    // S = Q.K^T  (scale already in q). B-operand slot j of lane = K[16n+m][k(g,j)]
    f32x4 s_acc[4];
#pragma unroll
    for (int n = 0; n < 4; ++n) {
      f32x4 z = vzero;
      z = MFMA16(qf[0], *(const bf16x8*)&Ks[16*n + m][g*8], z);
      z = MFMA16(qf[1], *(const bf16x8*)&Ks[16*n + m][32 + g*8], z);
      s_acc[n] = z;
    }

    // causal mask (diagonal tile only); within-tile indices suffice
    if (j == qt) {
#pragma unroll
      for (int n = 0; n < 4; ++n) {
        int gk = 16*n + m;
#pragma unroll
        for (int i = 0; i < 4; ++i) {
          int gq = 16*w + 4*g + i;
          if (gk > gq) s_acc[n][i] = -INFINITY;
        }
      }
    }

    // online softmax: per-lane state for rows 4g..4g+3, reduced over 16 lanes
    float corr[4], tsum[4];
#pragma unroll
    for (int i = 0; i < 4; ++i) {
      float mx = fmaxf(fmaxf(s_acc[0][i], s_acc[1][i]), fmaxf(s_acc[2][i], s_acc[3][i]));
      mx = fmaxf(mx, __shfl_xor(mx, 1));
      mx = fmaxf(mx, __shfl_xor(mx, 2));
      mx = fmaxf(mx, __shfl_xor(mx, 4));
      mx = fmaxf(mx, __shfl_xor(mx, 8));
      float mnew = fmaxf(mrun[i], mx);
      corr[i] = __expf(mrun[i] - mnew);   // exp(-inf)=0 on first tile
      mrun[i] = mnew;
      tsum[i] = 0.f;
    }
#pragma unroll
    for (int n = 0; n < 4; ++n) {
#pragma unroll
      for (int i = 0; i < 4; ++i) {
        float p = __expf(s_acc[n][i] - mrun[i]);
        tsum[i] += p;
        Ps[w][4*g + i][16*n + m] = (bf16)p;
      }
    }
#pragma unroll
    for (int i = 0; i < 4; ++i) {
      float s = tsum[i];
      s += __shfl_xor(s, 1);
      s += __shfl_xor(s, 2);
      s += __shfl_xor(s, 4);
      s += __shfl_xor(s, 8);
      lrun[i] = lrun[i] * corr[i] + s;
    }
#pragma unroll
    for (int n = 0; n < 4; ++n)
#pragma unroll
      for (int i = 0; i < 4; ++i)
        o_acc[n][i] *= corr[i];

    __syncthreads();  // make Ps writes visible (conservative; wave-uniform loop)

    // O += P.V : A = P (row=m), B = V (col=16n+m via V^T rows)
#pragma unroll
    for (int kk = 0; kk < 2; ++kk) {
      bf16x8 pf = *(const bf16x8*)&Ps[w][m][kk*32 + g*8];
#pragma unroll
      for (int n = 0; n < 4; ++n) {
        bf16x8 vf = *(const bf16x8*)&VTs[16*n + m][kk*32 + g*8];
        o_acc[n] = MFMA16(pf, vf, o_acc[n]);
      }
    }
  }

  const size_t obase = ((size_t)b * SEQ + qt*64 + 16*w) * HS;
#pragma unroll
  for (int n = 0; n < 4; ++n)
#pragma unroll
    for (int i = 0; i < 4; ++i)
      out[obase + (size_t)(4*g + i) * HS + 16*n + m] = o_acc[n][i] / lrun[i];
}

extern "C" void kernel_launch(void* const* d_in, const int* in_sizes, int n_in,
                              void* d_out, int out_size, void* d_ws, size_t ws_size,
                              hipStream_t stream) {
  (void)in_sizes; (void)n_in; (void)out_size; (void)ws_size;
  const float* index  = (const float*)d_in[0];
  const float* memory = (const float*)d_in[1];
  const float* Wq     = (const float*)d_in[2];
  const float* Wk     = (const float*)d_in[3];
  const float* Wv     = (const float*)d_in[4];
  float* out = (float*)d_out;

  // workspace: qb [NB*SEQ][64] bf16, kb same, vtb [NB][64][SEQ] bf16 (6 MiB total)
  bf16* qb  = (bf16*)d_ws;
  bf16* kb  = qb + (size_t)NB * SEQ * HS;
  bf16* vtb = kb + (size_t)NB * SEQ * HS;

  proj_kernel<0><<<dim3(256), 256, 0, stream>>>(index,  Wq, nullptr, qb, nullptr);
  proj_kernel<1><<<dim3(256), 256, 0, stream>>>(memory, Wk, Wv,      kb, vtb);
  attn_kernel<<<dim3(32, 8), 256, 0, stream>>>(qb, kb, vtb, out);
}

// Round 2
// 108.217 us; speedup vs baseline: 1.0834x; 1.0834x over previous
//
#include <hip/hip_runtime.h>
#include <math.h>

typedef __bf16 bf16;
typedef __bf16 bf16x8 __attribute__((ext_vector_type(8)));
typedef float f32x4 __attribute__((ext_vector_type(4)));

#define MFMA16(a,b,c) __builtin_amdgcn_mfma_f32_16x16x32_bf16((a),(b),(c),0,0,0)

static constexpr int HS  = 64;    // head size
static constexpr int SEQ = 2048;  // sequence length
static constexpr int NE  = 1024;  // n_embed
static constexpr int NB  = 8;     // batch

__device__ __forceinline__ bf16x8 cvt8(float4 a, float4 b) {
  bf16x8 r;
  r[0]=(bf16)a.x; r[1]=(bf16)a.y; r[2]=(bf16)a.z; r[3]=(bf16)a.w;
  r[4]=(bf16)b.x; r[5]=(bf16)b.y; r[6]=(bf16)b.z; r[7]=(bf16)b.w;
  return r;
}

// ---------------- unified projection ----------------
// Block = 256 thr (4 waves), 128 rows (wave w owns rows w*32..w*32+31 = 2 row-tiles).
// A-frags: direct global f32 -> reg -> cvt bf16 (one-tile prefetch, explicit ping-pong).
// W: bf16 in double-buffered LDS, one barrier per 64-wide K-tile.
template<int KV>
__device__ __forceinline__ void proj_body(
    const float* __restrict__ X, const float* __restrict__ Wa,
    const float* __restrict__ Wb, bf16* __restrict__ outA,
    bf16* __restrict__ outVT, int slab, bf16 (*Wlds)[2][64][72])
{
  const int tid  = threadIdx.x;
  const int lane = tid & 63;
  const int w    = tid >> 6;
  const int m    = lane & 15;
  const int g    = lane >> 4;
  const int rowBase = slab * 128 + w * 32;
  const int srow = tid >> 2;          // staging row 0..63
  const int sseg = (tid & 3) * 16;    // staging 16-col segment

  const float* xr = X  + (size_t)(rowBase + m) * NE + g * 8;
  const float* wa = Wa + (size_t)srow * NE + sseg;
  const float* wb = KV ? (Wb + (size_t)srow * NE + sseg) : nullptr;

  const f32x4 vz = {0.f,0.f,0.f,0.f};
  f32x4 acc[1+KV][2][4];
#pragma unroll
  for (int mt = 0; mt < 1+KV; ++mt)
#pragma unroll
    for (int rt = 0; rt < 2; ++rt)
#pragma unroll
      for (int n = 0; n < 4; ++n) acc[mt][rt][n] = vz;

  auto loadA = [&](int kt, float4 (&A)[2][2][2]) {
    const float* p0 = xr + kt * 64;
    const float* p1 = p0 + 16 * NE;
    A[0][0][0]=*(const float4*)(p0);      A[0][0][1]=*(const float4*)(p0+4);
    A[0][1][0]=*(const float4*)(p0+32);   A[0][1][1]=*(const float4*)(p0+36);
    A[1][0][0]=*(const float4*)(p1);      A[1][0][1]=*(const float4*)(p1+4);
    A[1][1][0]=*(const float4*)(p1+32);   A[1][1][1]=*(const float4*)(p1+36);
  };
  auto stageW = [&](int kt, int buf) {
    const float* p = wa + kt * 64;
    float4 x0=*(const float4*)(p),   x1=*(const float4*)(p+4);
    float4 x2=*(const float4*)(p+8), x3=*(const float4*)(p+12);
    *(bf16x8*)&Wlds[buf][0][srow][sseg]     = cvt8(x0,x1);
    *(bf16x8*)&Wlds[buf][0][srow][sseg + 8] = cvt8(x2,x3);
    if (KV) {
      const float* q = wb + kt * 64;
      float4 y0=*(const float4*)(q),   y1=*(const float4*)(q+4);
      float4 y2=*(const float4*)(q+8), y3=*(const float4*)(q+12);
      *(bf16x8*)&Wlds[buf][1][srow][sseg]     = cvt8(y0,y1);
      *(bf16x8*)&Wlds[buf][1][srow][sseg + 8] = cvt8(y2,y3);
    }
  };
  auto compute = [&](int buf, float4 (&A)[2][2][2]) {
    bf16x8 af[2][2];
    af[0][0]=cvt8(A[0][0][0],A[0][0][1]); af[0][1]=cvt8(A[0][1][0],A[0][1][1]);
    af[1][0]=cvt8(A[1][0][0],A[1][0][1]); af[1][1]=cvt8(A[1][1][0],A[1][1][1]);
#pragma unroll
    for (int kk = 0; kk < 2; ++kk)
#pragma unroll
      for (int n = 0; n < 4; ++n) {
        bf16x8 b0 = *(const bf16x8*)&Wlds[buf][0][16*n + m][kk*32 + g*8];
        acc[0][0][n] = MFMA16(af[0][kk], b0, acc[0][0][n]);
        acc[0][1][n] = MFMA16(af[1][kk], b0, acc[0][1][n]);
        if (KV) {
          bf16x8 b1 = *(const bf16x8*)&Wlds[buf][1][16*n + m][kk*32 + g*8];
          acc[1][0][n] = MFMA16(af[0][kk], b1, acc[1][0][n]);
          acc[1][1][n] = MFMA16(af[1][kk], b1, acc[1][1][n]);
        }
      }
  };

  float4 A0[2][2][2], A1[2][2][2];
  loadA(0, A0); stageW(0, 0);
  __syncthreads();
#pragma unroll
  for (int kt = 0; kt < 16; kt += 2) {
    if (kt + 1 < 16) { loadA(kt+1, A1); stageW(kt+1, 1); }
    compute(0, A0);
    __syncthreads();
    if (kt + 2 < 16) { loadA(kt+2, A0); stageW(kt+2, 0); }
    compute(1, A1);
    __syncthreads();
  }

  // C/D layout: col = lane&15 (=m), row = 4*(lane>>4)+i  [m89-verified]
#pragma unroll
  for (int rt = 0; rt < 2; ++rt)
#pragma unroll
    for (int n = 0; n < 4; ++n)
#pragma unroll
      for (int i = 0; i < 4; ++i) {
        int row = rowBase + 16*rt + 4*g + i;
        int h   = 16*n + m;
        if (!KV) {
          outA[(size_t)row * HS + h] = (bf16)(acc[0][rt][n][i] * 0.125f);
        } else {
          outA[(size_t)row * HS + h] = (bf16)acc[0][rt][n][i];
          outVT[((size_t)(row >> 11) * HS + h) * SEQ + (row & 2047)] =
              (bf16)acc[1][rt][n][i];
        }
      }
}

__global__ __launch_bounds__(256, 1) void proj_kernel(
    const float* __restrict__ index, const float* __restrict__ memory,
    const float* __restrict__ Wq, const float* __restrict__ Wk,
    const float* __restrict__ Wv, bf16* __restrict__ qb,
    bf16* __restrict__ kb, bf16* __restrict__ vtb)
{
  __shared__ __align__(16) bf16 Wlds[2][2][64][72];   // 36 KB
  if (blockIdx.x < 128)
    proj_body<0>(index,  Wq, nullptr, qb, nullptr, blockIdx.x, Wlds);
  else
    proj_body<1>(memory, Wk, Wv,      kb, vtb, blockIdx.x - 128, Wlds);
}

// ---------------- flash attention ----------------
// QBLK=32 (2 waves x 16 rows, 128 thr). grid (64, 8); qt reversed so the
// longest (most kv-steps) blocks dispatch first and short ones backfill.
// K/VT double-buffered: one barrier per kv-step.
__global__ __launch_bounds__(128) void attn_kernel(
    const bf16* __restrict__ qb, const bf16* __restrict__ kb,
    const bf16* __restrict__ vtb, float* __restrict__ out)
{
  __shared__ __align__(16) bf16 Ks[2][64][72];
  __shared__ __align__(16) bf16 VTs[2][64][72];
  __shared__ __align__(16) bf16 Ps[2][16][72];

  const int tid  = threadIdx.x;
  const int lane = tid & 63;
  const int w    = tid >> 6;      // 0..1
  const int m    = lane & 15;
  const int g    = lane >> 4;
  const int qt   = 63 - blockIdx.x;      // reversed for backfill balance
  const int b    = blockIdx.y;
  const int nkv  = (qt + 2) >> 1;        // ceil((qt*32+32)/64)
  const int srow = tid >> 1;
  const int sseg = (tid & 1) * 32;

  const int qrowA = qt*32 + 16*w + m;
  bf16x8 qf[2];
  qf[0] = *(const bf16x8*)(qb + ((size_t)b*SEQ + qrowA)*HS + g*8);
  qf[1] = *(const bf16x8*)(qb + ((size_t)b*SEQ + qrowA)*HS + 32 + g*8);

  auto stage = [&](int j, int buf) {
    const bf16* ks = kb  + ((size_t)b*SEQ + j*64 + srow)*HS + sseg;
    const bf16* vs = vtb + ((size_t)b*HS + srow)*SEQ + j*64 + sseg;
#pragma unroll
    for (int q8 = 0; q8 < 4; ++q8) {
      *(bf16x8*)&Ks[buf][srow][sseg + 8*q8]  = *(const bf16x8*)(ks + 8*q8);
      *(bf16x8*)&VTs[buf][srow][sseg + 8*q8] = *(const bf16x8*)(vs + 8*q8);
    }
  };

  const f32x4 vz = {0.f,0.f,0.f,0.f};
  f32x4 o_acc[4] = {vz, vz, vz, vz};
  float mrun[4], lrun[4];
#pragma unroll
  for (int i = 0; i < 4; ++i) { mrun[i] = -INFINITY; lrun[i] = 0.f; }

  stage(0, 0);
  __syncthreads();
  int cur = 0;

  for (int j = 0; j < nkv; ++j) {
    if (j + 1 < nkv) stage(j + 1, cur ^ 1);   // prefetch into other buffer

    // S = Q.K^T (scale baked into q)
    f32x4 s_acc[4];
#pragma unroll
    for (int n = 0; n < 4; ++n) {
      f32x4 z = vz;
      z = MFMA16(qf[0], *(const bf16x8*)&Ks[cur][16*n + m][g*8], z);
      z = MFMA16(qf[1], *(const bf16x8*)&Ks[cur][16*n + m][32 + g*8], z);
      s_acc[n] = z;
    }

    if (j == nkv - 1) {   // causal mask only ever needed on the last tile
#pragma unroll
      for (int n = 0; n < 4; ++n) {
        int gk = j*64 + 16*n + m;
#pragma unroll
        for (int i = 0; i < 4; ++i) {
          int gq = qt*32 + 16*w + 4*g + i;
          if (gk > gq) s_acc[n][i] = -INFINITY;
        }
      }
    }

    // online softmax (per-lane rows 4g+i, reduce across 16 m-lanes)
    float corr[4], tsum[4];
#pragma unroll
    for (int i = 0; i < 4; ++i) {
      float mx = fmaxf(fmaxf(s_acc[0][i], s_acc[1][i]), fmaxf(s_acc[2][i], s_acc[3][i]));
      mx = fmaxf(mx, __shfl_xor(mx, 1));
      mx = fmaxf(mx, __shfl_xor(mx, 2));
      mx = fmaxf(mx, __shfl_xor(mx, 4));
      mx = fmaxf(mx, __shfl_xor(mx, 8));
      float mnew = fmaxf(mrun[i], mx);
      corr[i] = __expf(mrun[i] - mnew);
      mrun[i] = mnew;
      tsum[i] = 0.f;
    }
#pragma unroll
    for (int n = 0; n < 4; ++n)
#pragma unroll
      for (int i = 0; i < 4; ++i) {
        float p = __expf(s_acc[n][i] - mrun[i]);
        tsum[i] += p;
        Ps[w][4*g + i][16*n + m] = (bf16)p;
      }
#pragma unroll
    for (int i = 0; i < 4; ++i) {
      float s = tsum[i];
      s += __shfl_xor(s, 1);
      s += __shfl_xor(s, 2);
      s += __shfl_xor(s, 4);
      s += __shfl_xor(s, 8);
      lrun[i] = lrun[i] * corr[i] + s;
    }
#pragma unroll
    for (int n = 0; n < 4; ++n)
#pragma unroll
      for (int i = 0; i < 4; ++i) o_acc[n][i] *= corr[i];

    // O += P.V  (Ps is per-wave: same-wave ds ordering, no barrier needed)
#pragma unroll
    for (int kk = 0; kk < 2; ++kk) {
      bf16x8 pf = *(const bf16x8*)&Ps[w][m][kk*32 + g*8];
#pragma unroll
      for (int n = 0; n < 4; ++n) {
        bf16x8 vf = *(const bf16x8*)&VTs[cur][16*n + m][kk*32 + g*8];
        o_acc[n] = MFMA16(pf, vf, o_acc[n]);
      }
    }

    __syncthreads();   // all waves done reading `cur`; prefetch writes visible
    cur ^= 1;
  }

  float inv[4];
#pragma unroll
  for (int i = 0; i < 4; ++i) inv[i] = 1.f / lrun[i];
  const size_t obase = ((size_t)b*SEQ + qt*32 + 16*w) * HS;
#pragma unroll
  for (int n = 0; n < 4; ++n)
#pragma unroll
    for (int i = 0; i < 4; ++i)
      out[obase + (size_t)(4*g + i)*HS + 16*n + m] = o_acc[n][i] * inv[i];
}

extern "C" void kernel_launch(void* const* d_in, const int* in_sizes, int n_in,
                              void* d_out, int out_size, void* d_ws, size_t ws_size,
                              hipStream_t stream) {
  (void)in_sizes; (void)n_in; (void)out_size; (void)ws_size;
  const float* index  = (const float*)d_in[0];
  const float* memory = (const float*)d_in[1];
  const float* Wq     = (const float*)d_in[2];
  const float* Wk     = (const float*)d_in[3];
  const float* Wv     = (const float*)d_in[4];
  float* out = (float*)d_out;

  bf16* qb  = (bf16*)d_ws;
  bf16* kb  = qb + (size_t)NB * SEQ * HS;
  bf16* vtb = kb + (size_t)NB * SEQ * HS;

  proj_kernel<<<dim3(256), 256, 0, stream>>>(index, memory, Wq, Wk, Wv, qb, kb, vtb);
  attn_kernel<<<dim3(64, 8), 128, 0, stream>>>(qb, kb, vtb, out);
}

// Round 3
// 97.889 us; speedup vs baseline: 1.1977x; 1.1055x over previous
//
#include <hip/hip_runtime.h>
#include <math.h>

typedef __bf16 bf16;
typedef __bf16 bf16x8 __attribute__((ext_vector_type(8)));
typedef float f32x4 __attribute__((ext_vector_type(4)));

#define MFMA16(a,b,c) __builtin_amdgcn_mfma_f32_16x16x32_bf16((a),(b),(c),0,0,0)

static constexpr int HS  = 64;    // head size
static constexpr int SEQ = 2048;  // sequence length
static constexpr int NE  = 1024;  // n_embed
static constexpr int NB  = 8;     // batch

__device__ __forceinline__ bf16x8 cvt8(float4 a, float4 b) {
  bf16x8 r;
  r[0]=(bf16)a.x; r[1]=(bf16)a.y; r[2]=(bf16)a.z; r[3]=(bf16)a.w;
  r[4]=(bf16)b.x; r[5]=(bf16)b.y; r[6]=(bf16)b.z; r[7]=(bf16)b.w;
  return r;
}

// ---------------- unified projection ----------------
// Block = 256 thr (4 waves), 64 rows; wave w owns rows 16w..16w+15.
// grid = 512 (2 blocks/CU): blocks 0..255 = Q slabs, 256..511 = K+V slabs.
// A: direct global f32 -> 8 NAMED float4 regs (ping-pong, no arrays -> no scratch).
// W: f32 -> bf16 cvt staged into double-buffered padded LDS.
template<int KV>
__device__ __forceinline__ void proj_body(
    const float* __restrict__ X, const float* __restrict__ Wa,
    const float* __restrict__ Wb, bf16* __restrict__ outA,
    bf16* __restrict__ outVT, int slab, bf16 (*Wlds)[2][64][72])
{
  const int tid  = threadIdx.x;
  const int lane = tid & 63;
  const int w    = tid >> 6;
  const int m    = lane & 15;
  const int g    = lane >> 4;
  const int srow = tid >> 2;          // staging row 0..63
  const int sseg = (tid & 3) * 16;    // staging 16-col segment
  const int rowBase = slab * 64;

  const float* xr = X  + (size_t)(rowBase + 16*w + m) * NE + g * 8;
  const float* wa = Wa + (size_t)srow * NE + sseg;
  const float* wb = KV ? (Wb + (size_t)srow * NE + sseg) : nullptr;

  const f32x4 vz = {0.f,0.f,0.f,0.f};
  f32x4 accA[4] = {vz, vz, vz, vz};
  f32x4 accB[4] = {vz, vz, vz, vz};   // unused (DCE'd) when !KV

  float4 c0, c1, c2, c3;   // current A tile (rows m, cols g*8|+4|32+g*8|+36)
  float4 p0, p1, p2, p3;   // prefetched A tile

#define LOAD_A(kt, d0, d1, d2, d3) do {            \
    const float* _p = xr + (kt) * 64;              \
    d0 = *(const float4*)(_p);                     \
    d1 = *(const float4*)(_p + 4);                 \
    d2 = *(const float4*)(_p + 32);                \
    d3 = *(const float4*)(_p + 36);                \
  } while (0)

  auto stageW = [&](int kt, int buf) {
    const float* p = wa + kt * 64;
    float4 x0=*(const float4*)(p),   x1=*(const float4*)(p+4);
    float4 x2=*(const float4*)(p+8), x3=*(const float4*)(p+12);
    *(bf16x8*)&Wlds[buf][0][srow][sseg]     = cvt8(x0,x1);
    *(bf16x8*)&Wlds[buf][0][srow][sseg + 8] = cvt8(x2,x3);
    if (KV) {
      const float* q = wb + kt * 64;
      float4 y0=*(const float4*)(q),   y1=*(const float4*)(q+4);
      float4 y2=*(const float4*)(q+8), y3=*(const float4*)(q+12);
      *(bf16x8*)&Wlds[buf][1][srow][sseg]     = cvt8(y0,y1);
      *(bf16x8*)&Wlds[buf][1][srow][sseg + 8] = cvt8(y2,y3);
    }
  };

  auto compute = [&](int buf, float4 a0, float4 a1, float4 a2, float4 a3) {
    bf16x8 af0 = cvt8(a0, a1);        // kk=0 fragment
    bf16x8 af1 = cvt8(a2, a3);        // kk=1 fragment
#pragma unroll
    for (int n = 0; n < 4; ++n) {
      bf16x8 b00 = *(const bf16x8*)&Wlds[buf][0][16*n + m][g*8];
      bf16x8 b01 = *(const bf16x8*)&Wlds[buf][0][16*n + m][32 + g*8];
      accA[n] = MFMA16(af0, b00, accA[n]);
      accA[n] = MFMA16(af1, b01, accA[n]);
      if (KV) {
        bf16x8 b10 = *(const bf16x8*)&Wlds[buf][1][16*n + m][g*8];
        bf16x8 b11 = *(const bf16x8*)&Wlds[buf][1][16*n + m][32 + g*8];
        accB[n] = MFMA16(af0, b10, accB[n]);
        accB[n] = MFMA16(af1, b11, accB[n]);
      }
    }
  };

  LOAD_A(0, c0, c1, c2, c3);
  stageW(0, 0);
  __syncthreads();

  for (int kt = 0; kt < 16; kt += 2) {
    if (kt + 1 < 16) { LOAD_A(kt+1, p0, p1, p2, p3); stageW(kt+1, 1); }
    compute(0, c0, c1, c2, c3);
    __syncthreads();
    if (kt + 2 < 16) { LOAD_A(kt+2, c0, c1, c2, c3); stageW(kt+2, 0); }
    compute(1, p0, p1, p2, p3);
    __syncthreads();
  }
#undef LOAD_A

  // C/D layout: col = lane&15 (=m), row = 4*(lane>>4)+i  [m89-verified]
#pragma unroll
  for (int n = 0; n < 4; ++n)
#pragma unroll
    for (int i = 0; i < 4; ++i) {
      int row = rowBase + 16*w + 4*g + i;
      int h   = 16*n + m;
      if (!KV) {
        outA[(size_t)row * HS + h] = (bf16)(accA[n][i] * 0.125f);  // q * 1/sqrt(64)
      } else {
        outA[(size_t)row * HS + h] = (bf16)accA[n][i];
        outVT[((size_t)(row >> 11) * HS + h) * SEQ + (row & 2047)] =
            (bf16)accB[n][i];
      }
    }
}

__global__ __launch_bounds__(256) void proj_kernel(
    const float* __restrict__ index, const float* __restrict__ memory,
    const float* __restrict__ Wq, const float* __restrict__ Wk,
    const float* __restrict__ Wv, bf16* __restrict__ qb,
    bf16* __restrict__ kb, bf16* __restrict__ vtb)
{
  __shared__ __align__(16) bf16 Wlds[2][2][64][72];   // 36 KB
  if (blockIdx.x < 256)
    proj_body<0>(index,  Wq, nullptr, qb, nullptr, blockIdx.x, Wlds);
  else
    proj_body<1>(memory, Wk, Wv,      kb, vtb, blockIdx.x - 256, Wlds);
}

// ---------------- flash attention ----------------
// QBLK=32 (2 waves x 16 rows, 128 thr). grid (64, 8); qt reversed so the
// longest blocks dispatch first and short ones backfill.
__global__ __launch_bounds__(128) void attn_kernel(
    const bf16* __restrict__ qb, const bf16* __restrict__ kb,
    const bf16* __restrict__ vtb, float* __restrict__ out)
{
  __shared__ __align__(16) bf16 Ks[2][64][72];
  __shared__ __align__(16) bf16 VTs[2][64][72];
  __shared__ __align__(16) bf16 Ps[2][16][72];

  const int tid  = threadIdx.x;
  const int lane = tid & 63;
  const int w    = tid >> 6;      // 0..1
  const int m    = lane & 15;
  const int g    = lane >> 4;
  const int qt   = 63 - blockIdx.x;      // reversed for backfill balance
  const int b    = blockIdx.y;
  const int nkv  = (qt + 2) >> 1;        // ceil((qt*32+32)/64)
  const int srow = tid >> 1;
  const int sseg = (tid & 1) * 32;

  const int qrowA = qt*32 + 16*w + m;
  bf16x8 qf[2];
  qf[0] = *(const bf16x8*)(qb + ((size_t)b*SEQ + qrowA)*HS + g*8);
  qf[1] = *(const bf16x8*)(qb + ((size_t)b*SEQ + qrowA)*HS + 32 + g*8);

  auto stage = [&](int j, int buf) {
    const bf16* ks = kb  + ((size_t)b*SEQ + j*64 + srow)*HS + sseg;
    const bf16* vs = vtb + ((size_t)b*HS + srow)*SEQ + j*64 + sseg;
#pragma unroll
    for (int q8 = 0; q8 < 4; ++q8) {
      *(bf16x8*)&Ks[buf][srow][sseg + 8*q8]  = *(const bf16x8*)(ks + 8*q8);
      *(bf16x8*)&VTs[buf][srow][sseg + 8*q8] = *(const bf16x8*)(vs + 8*q8);
    }
  };

  const f32x4 vz = {0.f,0.f,0.f,0.f};
  f32x4 o_acc[4] = {vz, vz, vz, vz};
  float mrun[4], lrun[4];
#pragma unroll
  for (int i = 0; i < 4; ++i) { mrun[i] = -INFINITY; lrun[i] = 0.f; }

  stage(0, 0);
  __syncthreads();
  int cur = 0;

  for (int j = 0; j < nkv; ++j) {
    if (j + 1 < nkv) stage(j + 1, cur ^ 1);   // prefetch into other buffer

    // S = Q.K^T (scale baked into q)
    f32x4 s_acc[4];
#pragma unroll
    for (int n = 0; n < 4; ++n) {
      f32x4 z = vz;
      z = MFMA16(qf[0], *(const bf16x8*)&Ks[cur][16*n + m][g*8], z);
      z = MFMA16(qf[1], *(const bf16x8*)&Ks[cur][16*n + m][32 + g*8], z);
      s_acc[n] = z;
    }

    if (j == nkv - 1) {   // causal mask needed only on the diagonal tile
#pragma unroll
      for (int n = 0; n < 4; ++n) {
        int gk = j*64 + 16*n + m;
#pragma unroll
        for (int i = 0; i < 4; ++i) {
          int gq = qt*32 + 16*w + 4*g + i;
          if (gk > gq) s_acc[n][i] = -INFINITY;
        }
      }
    }

    // online softmax (per-lane rows 4g+i, reduce across 16 m-lanes)
    float corr[4], tsum[4];
#pragma unroll
    for (int i = 0; i < 4; ++i) {
      float mx = fmaxf(fmaxf(s_acc[0][i], s_acc[1][i]), fmaxf(s_acc[2][i], s_acc[3][i]));
      mx = fmaxf(mx, __shfl_xor(mx, 1));
      mx = fmaxf(mx, __shfl_xor(mx, 2));
      mx = fmaxf(mx, __shfl_xor(mx, 4));
      mx = fmaxf(mx, __shfl_xor(mx, 8));
      float mnew = fmaxf(mrun[i], mx);
      corr[i] = __expf(mrun[i] - mnew);
      mrun[i] = mnew;
      tsum[i] = 0.f;
    }
#pragma unroll
    for (int n = 0; n < 4; ++n)
#pragma unroll
      for (int i = 0; i < 4; ++i) {
        float p = __expf(s_acc[n][i] - mrun[i]);
        tsum[i] += p;
        Ps[w][4*g + i][16*n + m] = (bf16)p;
      }
#pragma unroll
    for (int i = 0; i < 4; ++i) {
      float s = tsum[i];
      s += __shfl_xor(s, 1);
      s += __shfl_xor(s, 2);
      s += __shfl_xor(s, 4);
      s += __shfl_xor(s, 8);
      lrun[i] = lrun[i] * corr[i] + s;
    }
#pragma unroll
    for (int n = 0; n < 4; ++n)
#pragma unroll
      for (int i = 0; i < 4; ++i) o_acc[n][i] *= corr[i];

    // O += P.V  (Ps is per-wave: same-wave ds ordering, no barrier needed)
#pragma unroll
    for (int kk = 0; kk < 2; ++kk) {
      bf16x8 pf = *(const bf16x8*)&Ps[w][m][kk*32 + g*8];
#pragma unroll
      for (int n = 0; n < 4; ++n) {
        bf16x8 vf = *(const bf16x8*)&VTs[cur][16*n + m][kk*32 + g*8];
        o_acc[n] = MFMA16(pf, vf, o_acc[n]);
      }
    }

    __syncthreads();   // all waves done reading `cur`; prefetch writes visible
    cur ^= 1;
  }

  float inv[4];
#pragma unroll
  for (int i = 0; i < 4; ++i) inv[i] = 1.f / lrun[i];
  const size_t obase = ((size_t)b*SEQ + qt*32 + 16*w) * HS;
#pragma unroll
  for (int n = 0; n < 4; ++n)
#pragma unroll
    for (int i = 0; i < 4; ++i)
      out[obase + (size_t)(4*g + i)*HS + 16*n + m] = o_acc[n][i] * inv[i];
}

extern "C" void kernel_launch(void* const* d_in, const int* in_sizes, int n_in,
                              void* d_out, int out_size, void* d_ws, size_t ws_size,
                              hipStream_t stream) {
  (void)in_sizes; (void)n_in; (void)out_size; (void)ws_size;
  const float* index  = (const float*)d_in[0];
  const float* memory = (const float*)d_in[1];
  const float* Wq     = (const float*)d_in[2];
  const float* Wk     = (const float*)d_in[3];
  const float* Wv     = (const float*)d_in[4];
  float* out = (float*)d_out;

  bf16* qb  = (bf16*)d_ws;
  bf16* kb  = qb + (size_t)NB * SEQ * HS;
  bf16* vtb = kb + (size_t)NB * SEQ * HS;

  proj_kernel<<<dim3(512), 256, 0, stream>>>(index, memory, Wq, Wk, Wv, qb, kb, vtb);
  attn_kernel<<<dim3(64, 8), 128, 0, stream>>>(qb, kb, vtb, out);
}